// Round 7
// baseline (1317.458 us; speedup 1.0000x reference)
//
#include <hip/hip_runtime.h>

#define N_NODES 100000
#define N_EDGES 1600000
#define IN_F 128
#define HID_F 64
#define OUT_F 40
#define N_STEPS 10

static constexpr float DT = 0.1f;
static constexpr float ONE_MINUS_DT = 0.9f;
// SIGMA * sqrt(DT) = 0.01 * sqrt(0.1)
static constexpr float C_NOISE = 0.0031622776601683794f;

// ---------------- degree histograms (int) ----------------
__global__ __launch_bounds__(256) void deg_kernel(const int* __restrict__ src,
                                                  const int* __restrict__ dst,
                                                  int* __restrict__ deg_out,
                                                  int* __restrict__ deg_in) {
    int i = blockIdx.x * 256 + threadIdx.x;
    if (i < N_EDGES) {
        atomicAdd(&deg_out[src[i]], 1);
        atomicAdd(&deg_in[dst[i]], 1);
    }
}

// ---------------- per-node scale factors ----------------
__global__ __launch_bounds__(256) void scale_kernel(const int* __restrict__ deg_out,
                                                    const int* __restrict__ deg_in,
                                                    float* __restrict__ a,
                                                    float* __restrict__ b) {
    int i = blockIdx.x * 256 + threadIdx.x;
    if (i < N_NODES) {
        a[i] = rsqrtf((float)max(deg_out[i], 1));
        b[i] = rsqrtf((float)max(deg_in[i], 1));
    }
}

// ---------------- 3-kernel exclusive scan of deg_in -> row_ptr ----------------
__global__ __launch_bounds__(256) void scan_blocksum_kernel(const int* __restrict__ deg,
                                                            int* __restrict__ blocksum) {
    __shared__ int buf[256];
    int i = blockIdx.x * 256 + threadIdx.x;
    buf[threadIdx.x] = (i < N_NODES) ? deg[i] : 0;
    __syncthreads();
    for (int off = 128; off > 0; off >>= 1) {
        if (threadIdx.x < off) buf[threadIdx.x] += buf[threadIdx.x + off];
        __syncthreads();
    }
    if (threadIdx.x == 0) blocksum[blockIdx.x] = buf[0];
}

__global__ __launch_bounds__(512) void scan_top_kernel(const int* __restrict__ blocksum,
                                                       int* __restrict__ blockpfx,
                                                       int nblocks) {
    __shared__ int buf[512];
    int v = (threadIdx.x < nblocks) ? blocksum[threadIdx.x] : 0;
    buf[threadIdx.x] = v;
    __syncthreads();
    for (int off = 1; off < 512; off <<= 1) {
        int t = (threadIdx.x >= off) ? buf[threadIdx.x - off] : 0;
        __syncthreads();
        buf[threadIdx.x] += t;
        __syncthreads();
    }
    if (threadIdx.x < nblocks) blockpfx[threadIdx.x] = buf[threadIdx.x] - v;
}

__global__ __launch_bounds__(256) void scan_final_kernel(const int* __restrict__ deg,
                                                         const int* __restrict__ blockpfx,
                                                         int* __restrict__ row_ptr,
                                                         int* __restrict__ cursor) {
    __shared__ int buf[256];
    int i = blockIdx.x * 256 + threadIdx.x;
    int v = (i < N_NODES) ? deg[i] : 0;
    buf[threadIdx.x] = v;
    __syncthreads();
    for (int off = 1; off < 256; off <<= 1) {
        int t = (threadIdx.x >= off) ? buf[threadIdx.x - off] : 0;
        __syncthreads();
        buf[threadIdx.x] += t;
        __syncthreads();
    }
    int excl = blockpfx[blockIdx.x] + buf[threadIdx.x] - v;
    if (i < N_NODES) {
        row_ptr[i] = excl;
        cursor[i] = excl;
    }
    if (blockIdx.x == gridDim.x - 1 && threadIdx.x == 255)
        row_ptr[N_NODES] = blockpfx[blockIdx.x] + buf[255];
}

// ---------------- CSR fill: bucket edges by dst ----------------
__global__ __launch_bounds__(256) void fill_kernel(const int* __restrict__ src,
                                                   const int* __restrict__ dst,
                                                   int* __restrict__ cursor,
                                                   int* __restrict__ src_sorted) {
    int e = blockIdx.x * 256 + threadIdx.x;
    if (e < N_EDGES) {
        int pos = atomicAdd(&cursor[dst[e]], 1);
        src_sorted[pos] = src[e];
    }
}

// ---------------- register-W row GEMM ----------------
// Y[r, 0..NCOL) = (A[r, 0..K) @ W[K, NCOL]) * (SCALE ? scale[r] : 1)
// One wave per RPW rows. Lane j holds column j of W in VGPRs (wreg[K]).
// A-row elements are wave-uniform -> scalar (SGPR) loads; pure v_fma with
// SGPR operand; zero LDS, zero shuffles. 4 rows interleaved for ILP.
template <int K, int NCOL, int RPW, bool SCALE>
__global__ __launch_bounds__(256) void regw_mm_kernel(const float* __restrict__ A,
                                                      const float* __restrict__ W,
                                                      float* __restrict__ Y,
                                                      const float* __restrict__ scale,
                                                      int nwaves) {
    int lane = threadIdx.x & 63;
    int wid = __builtin_amdgcn_readfirstlane((blockIdx.x * 256 + threadIdx.x) >> 6);
    if (wid >= nwaves) return;

    float wreg[K];
#pragma unroll
    for (int k = 0; k < K; k++)
        wreg[k] = (lane < NCOL) ? W[k * NCOL + lane] : 0.0f;

    int r0 = wid * RPW;
#pragma unroll 1
    for (int rr = 0; rr < RPW; rr += 4) {
        int r = r0 + rr;
        const float* a0 = A + (size_t)(r + 0) * K;
        const float* a1 = A + (size_t)(r + 1) * K;
        const float* a2 = A + (size_t)(r + 2) * K;
        const float* a3 = A + (size_t)(r + 3) * K;
        float acc0 = 0.f, acc1 = 0.f, acc2 = 0.f, acc3 = 0.f;
#pragma unroll
        for (int k = 0; k < K; k++) {
            float w = wreg[k];
            acc0 = fmaf(a0[k], w, acc0);
            acc1 = fmaf(a1[k], w, acc1);
            acc2 = fmaf(a2[k], w, acc2);
            acc3 = fmaf(a3[k], w, acc3);
        }
        if (lane < NCOL) {
            if (SCALE) {
                acc0 *= scale[r + 0];
                acc1 *= scale[r + 1];
                acc2 *= scale[r + 2];
                acc3 *= scale[r + 3];
            }
            Y[(size_t)(r + 0) * NCOL + lane] = acc0;
            Y[(size_t)(r + 1) * NCOL + lane] = acc1;
            Y[(size_t)(r + 2) * NCOL + lane] = acc2;
            Y[(size_t)(r + 3) * NCOL + lane] = acc3;
        }
    }
}

// ---------------- fused gather + Euler-Maruyama update ----------------
// one wave (64 lanes) per dst node; lane = feature.
// x[d] = 0.9*x[d] + 0.1*b[d]*sum_{e in CSR[d]} m[src_e] + C_NOISE*dW[d]
__global__ __launch_bounds__(256) void gather_update_kernel(const float* __restrict__ m,
                                                            const int* __restrict__ row_ptr,
                                                            const int* __restrict__ src_sorted,
                                                            const float* __restrict__ b,
                                                            float* __restrict__ x,
                                                            const float* __restrict__ dw) {
    int d = blockIdx.x * 4 + (threadIdx.x >> 6);
    int lane = threadIdx.x & 63;
    if (d >= N_NODES) return;

    int beg = row_ptr[d];
    int end = row_ptr[d + 1];

    float acc0 = 0.f, acc1 = 0.f, acc2 = 0.f, acc3 = 0.f;
    int j = beg;
    while (j < end) {
        int cnt = min(end - j, 64);
        int idx = (lane < cnt) ? src_sorted[j + lane] : 0;
        int jj = 0;
        for (; jj + 4 <= cnt; jj += 4) {
            int s0 = __shfl(idx, jj + 0);
            int s1 = __shfl(idx, jj + 1);
            int s2 = __shfl(idx, jj + 2);
            int s3 = __shfl(idx, jj + 3);
            acc0 += m[(size_t)s0 * HID_F + lane];
            acc1 += m[(size_t)s1 * HID_F + lane];
            acc2 += m[(size_t)s2 * HID_F + lane];
            acc3 += m[(size_t)s3 * HID_F + lane];
        }
        for (; jj < cnt; ++jj)
            acc0 += m[(size_t)__shfl(idx, jj) * HID_F + lane];
        j += cnt;
    }
    float acc = (acc0 + acc1) + (acc2 + acc3);

    size_t o = (size_t)d * HID_F + lane;
    float xv = x[o];
    x[o] = ONE_MINUS_DT * xv + (DT * b[d]) * acc + C_NOISE * dw[o];
}

extern "C" void kernel_launch(void* const* d_in, const int* in_sizes, int n_in,
                              void* d_out, int out_size, void* d_ws, size_t ws_size,
                              hipStream_t stream) {
    const float* h     = (const float*)d_in[0];
    const float* W_in  = (const float*)d_in[1];
    const float* W_msg = (const float*)d_in[2];
    const float* W_out = (const float*)d_in[3];
    const float* dW    = (const float*)d_in[4];
    const int*   src   = (const int*)d_in[5];
    const int*   dst   = (const int*)d_in[6];
    float* out = (float*)d_out;

    const size_t NH = (size_t)N_NODES * HID_F;  // 6.4M
    const int NBLK = (N_NODES + 255) / 256;     // 391

    float* x       = (float*)d_ws;              // 6.4M f
    float* m       = x + NH;                    // 6.4M f
    float* a       = m + NH;                    // 100K f
    float* b       = a + N_NODES;               // 100K f
    int* deg_out_i = (int*)(b + N_NODES);       // 100K i
    int* deg_in_i  = deg_out_i + N_NODES;       // 100K i
    int* row_ptr   = deg_in_i + N_NODES;        // 100K+1 i
    int* cursor    = row_ptr + N_NODES + 1;     // 100K+1 i
    int* blocksum  = cursor + N_NODES + 1;      // 391 i
    int* blockpfx  = blocksum + 512;            // 391 i
    int* src_sorted= blockpfx + 512;            // 1.6M i

    // ---- one-time per launch: degrees, scales, CSR ----
    hipMemsetAsync(deg_out_i, 0, 2 * N_NODES * sizeof(int), stream);
    {
        dim3 ge((N_EDGES + 255) / 256);
        deg_kernel<<<ge, 256, 0, stream>>>(src, dst, deg_out_i, deg_in_i);
        scale_kernel<<<dim3(NBLK), 256, 0, stream>>>(deg_out_i, deg_in_i, a, b);
        scan_blocksum_kernel<<<dim3(NBLK), 256, 0, stream>>>(deg_in_i, blocksum);
        scan_top_kernel<<<1, 512, 0, stream>>>(blocksum, blockpfx, NBLK);
        scan_final_kernel<<<dim3(NBLK), 256, 0, stream>>>(deg_in_i, blockpfx, row_ptr, cursor);
        fill_kernel<<<ge, 256, 0, stream>>>(src, dst, cursor, src_sorted);
    }

    // ---- x = h @ W_in ----
    {
        const int nwaves = N_NODES / 16;                // 6250 (RPW=16)
        const int grid = (nwaves + 3) / 4;              // 1563
        regw_mm_kernel<IN_F, HID_F, 16, false><<<dim3(grid), 256, 0, stream>>>(
            h, W_in, x, nullptr, nwaves);
    }

    // ---- 10 Euler-Maruyama steps: m = a*(x@W_msg); x = gather-update ----
    const int nwaves_msg = N_NODES / 8;                 // 12500 (RPW=8)
    const dim3 g_msg((nwaves_msg + 3) / 4);             // 3125
    const dim3 g_gather((N_NODES + 3) / 4);             // 25000
    for (int k = 0; k < N_STEPS; k++) {
        regw_mm_kernel<HID_F, HID_F, 8, true><<<g_msg, 256, 0, stream>>>(
            x, W_msg, m, a, nwaves_msg);
        gather_update_kernel<<<g_gather, 256, 0, stream>>>(m, row_ptr, src_sorted, b, x,
                                                           dW + (size_t)k * NH);
    }

    // ---- out = x @ W_out ----
    {
        const int nwaves = N_NODES / 8;                 // 12500 (RPW=8)
        regw_mm_kernel<HID_F, OUT_F, 8, false><<<dim3((nwaves + 3) / 4), 256, 0, stream>>>(
            x, W_out, out, nullptr, nwaves);
    }
}

// Round 8
// 1197.441 us; speedup vs baseline: 1.1002x; 1.1002x over previous
//
#include <hip/hip_runtime.h>

#define N_NODES 100000
#define N_EDGES 1600000
#define IN_F 128
#define HID_F 64
#define OUT_F 40
#define N_STEPS 10

static constexpr float DT = 0.1f;
static constexpr float ONE_MINUS_DT = 0.9f;
// SIGMA * sqrt(DT) = 0.01 * sqrt(0.1)
static constexpr float C_NOISE = 0.0031622776601683794f;

typedef unsigned short bf16_t;

// f32 -> bf16 round-to-nearest-even (finite values only)
static __device__ __forceinline__ bf16_t f2bf(float f) {
    union { float f; unsigned u; } v; v.f = f;
    unsigned r = v.u + 0x7fffu + ((v.u >> 16) & 1u);
    return (bf16_t)(r >> 16);
}
static __device__ __forceinline__ float bf2f(bf16_t h) {
    union { unsigned u; float f; } v; v.u = ((unsigned)h) << 16;
    return v.f;
}

// ---------------- degree histograms (int) ----------------
__global__ __launch_bounds__(256) void deg_kernel(const int* __restrict__ src,
                                                  const int* __restrict__ dst,
                                                  int* __restrict__ deg_out,
                                                  int* __restrict__ deg_in) {
    int i = blockIdx.x * 256 + threadIdx.x;
    if (i < N_EDGES) {
        atomicAdd(&deg_out[src[i]], 1);
        atomicAdd(&deg_in[dst[i]], 1);
    }
}

// ---------------- per-node scale factors ----------------
__global__ __launch_bounds__(256) void scale_kernel(const int* __restrict__ deg_out,
                                                    const int* __restrict__ deg_in,
                                                    float* __restrict__ a,
                                                    float* __restrict__ b) {
    int i = blockIdx.x * 256 + threadIdx.x;
    if (i < N_NODES) {
        a[i] = rsqrtf((float)max(deg_out[i], 1));
        b[i] = rsqrtf((float)max(deg_in[i], 1));
    }
}

// ---------------- 3-kernel exclusive scan of deg_in -> row_ptr ----------------
__global__ __launch_bounds__(256) void scan_blocksum_kernel(const int* __restrict__ deg,
                                                            int* __restrict__ blocksum) {
    __shared__ int buf[256];
    int i = blockIdx.x * 256 + threadIdx.x;
    buf[threadIdx.x] = (i < N_NODES) ? deg[i] : 0;
    __syncthreads();
    for (int off = 128; off > 0; off >>= 1) {
        if (threadIdx.x < off) buf[threadIdx.x] += buf[threadIdx.x + off];
        __syncthreads();
    }
    if (threadIdx.x == 0) blocksum[blockIdx.x] = buf[0];
}

__global__ __launch_bounds__(512) void scan_top_kernel(const int* __restrict__ blocksum,
                                                       int* __restrict__ blockpfx,
                                                       int nblocks) {
    __shared__ int buf[512];
    int v = (threadIdx.x < nblocks) ? blocksum[threadIdx.x] : 0;
    buf[threadIdx.x] = v;
    __syncthreads();
    for (int off = 1; off < 512; off <<= 1) {
        int t = (threadIdx.x >= off) ? buf[threadIdx.x - off] : 0;
        __syncthreads();
        buf[threadIdx.x] += t;
        __syncthreads();
    }
    if (threadIdx.x < nblocks) blockpfx[threadIdx.x] = buf[threadIdx.x] - v;
}

__global__ __launch_bounds__(256) void scan_final_kernel(const int* __restrict__ deg,
                                                         const int* __restrict__ blockpfx,
                                                         int* __restrict__ row_ptr,
                                                         int* __restrict__ cursor) {
    __shared__ int buf[256];
    int i = blockIdx.x * 256 + threadIdx.x;
    int v = (i < N_NODES) ? deg[i] : 0;
    buf[threadIdx.x] = v;
    __syncthreads();
    for (int off = 1; off < 256; off <<= 1) {
        int t = (threadIdx.x >= off) ? buf[threadIdx.x - off] : 0;
        __syncthreads();
        buf[threadIdx.x] += t;
        __syncthreads();
    }
    int excl = blockpfx[blockIdx.x] + buf[threadIdx.x] - v;
    if (i < N_NODES) {
        row_ptr[i] = excl;
        cursor[i] = excl;
    }
    if (blockIdx.x == gridDim.x - 1 && threadIdx.x == 255)
        row_ptr[N_NODES] = blockpfx[blockIdx.x] + buf[255];
}

// ---------------- CSR fill: bucket edges by dst ----------------
__global__ __launch_bounds__(256) void fill_kernel(const int* __restrict__ src,
                                                   const int* __restrict__ dst,
                                                   int* __restrict__ cursor,
                                                   int* __restrict__ src_sorted) {
    int e = blockIdx.x * 256 + threadIdx.x;
    if (e < N_EDGES) {
        int pos = atomicAdd(&cursor[dst[e]], 1);
        src_sorted[pos] = src[e];
    }
}

// ---------------- register-W row GEMM ----------------
// Y[r, 0..NCOL) = (A[r, 0..K) @ W[K, NCOL]) * (SCALE ? scale[r] : 1)
// One wave per RPW rows. Lane j holds column j of W in VGPRs.
// A-row elements wave-uniform -> scalar loads; pure v_fma with SGPR operand.
// BF16OUT: store bf16 (RNE) instead of f32.
template <int K, int NCOL, int RPW, bool SCALE, bool BF16OUT>
__global__ __launch_bounds__(256) void regw_mm_kernel(const float* __restrict__ A,
                                                      const float* __restrict__ W,
                                                      void* __restrict__ Yv,
                                                      const float* __restrict__ scale,
                                                      int nwaves) {
    int lane = threadIdx.x & 63;
    int wid = __builtin_amdgcn_readfirstlane((blockIdx.x * 256 + threadIdx.x) >> 6);
    if (wid >= nwaves) return;

    float wreg[K];
#pragma unroll
    for (int k = 0; k < K; k++)
        wreg[k] = (lane < NCOL) ? W[k * NCOL + lane] : 0.0f;

    float* Yf = (float*)Yv;
    bf16_t* Yb = (bf16_t*)Yv;

    int r0 = wid * RPW;
#pragma unroll 1
    for (int rr = 0; rr < RPW; rr += 4) {
        int r = r0 + rr;
        const float* a0 = A + (size_t)(r + 0) * K;
        const float* a1 = A + (size_t)(r + 1) * K;
        const float* a2 = A + (size_t)(r + 2) * K;
        const float* a3 = A + (size_t)(r + 3) * K;
        float acc0 = 0.f, acc1 = 0.f, acc2 = 0.f, acc3 = 0.f;
#pragma unroll
        for (int k = 0; k < K; k++) {
            float w = wreg[k];
            acc0 = fmaf(a0[k], w, acc0);
            acc1 = fmaf(a1[k], w, acc1);
            acc2 = fmaf(a2[k], w, acc2);
            acc3 = fmaf(a3[k], w, acc3);
        }
        if (lane < NCOL) {
            if (SCALE) {
                acc0 *= scale[r + 0];
                acc1 *= scale[r + 1];
                acc2 *= scale[r + 2];
                acc3 *= scale[r + 3];
            }
            if (BF16OUT) {
                Yb[(size_t)(r + 0) * NCOL + lane] = f2bf(acc0);
                Yb[(size_t)(r + 1) * NCOL + lane] = f2bf(acc1);
                Yb[(size_t)(r + 2) * NCOL + lane] = f2bf(acc2);
                Yb[(size_t)(r + 3) * NCOL + lane] = f2bf(acc3);
            } else {
                Yf[(size_t)(r + 0) * NCOL + lane] = acc0;
                Yf[(size_t)(r + 1) * NCOL + lane] = acc1;
                Yf[(size_t)(r + 2) * NCOL + lane] = acc2;
                Yf[(size_t)(r + 3) * NCOL + lane] = acc3;
            }
        }
    }
}

// ---------------- fused gather + Euler-Maruyama update (bf16 m) ----------------
// One wave per dst node. 4 edges processed concurrently: 16-lane group g takes
// edge jj+g, each lane loads ushort4 (8B) = 4 features at position p=lane&15.
// Cross-group shfl_xor reduce, then 16-lane float4 update of x.
__global__ __launch_bounds__(256) void gather_update_kernel(const bf16_t* __restrict__ m,
                                                            const int* __restrict__ row_ptr,
                                                            const int* __restrict__ src_sorted,
                                                            const float* __restrict__ b,
                                                            float* __restrict__ x,
                                                            const float* __restrict__ dw) {
    int d = blockIdx.x * 4 + (threadIdx.x >> 6);
    int lane = threadIdx.x & 63;
    int g = lane >> 4;
    int p = lane & 15;

    int beg = row_ptr[d];
    int end = row_ptr[d + 1];

    float acc0 = 0.f, acc1 = 0.f, acc2 = 0.f, acc3 = 0.f;
    int j = beg;
    while (j < end) {
        int cnt = min(end - j, 64);
        int idx = (lane < cnt) ? src_sorted[j + lane] : 0;
#pragma unroll 2
        for (int jj = 0; jj < cnt; jj += 4) {
            int e = jj + g;
            int s = __shfl(idx, min(e, cnt - 1));
            if (e < cnt) {
                ushort4 mv = *reinterpret_cast<const ushort4*>(m + (size_t)s * HID_F + p * 4);
                acc0 += bf2f(mv.x);
                acc1 += bf2f(mv.y);
                acc2 += bf2f(mv.z);
                acc3 += bf2f(mv.w);
            }
        }
        j += cnt;
    }

    // reduce across the 4 edge-groups (lanes p, p+16, p+32, p+48)
    acc0 += __shfl_xor(acc0, 16);
    acc1 += __shfl_xor(acc1, 16);
    acc2 += __shfl_xor(acc2, 16);
    acc3 += __shfl_xor(acc3, 16);
    acc0 += __shfl_xor(acc0, 32);
    acc1 += __shfl_xor(acc1, 32);
    acc2 += __shfl_xor(acc2, 32);
    acc3 += __shfl_xor(acc3, 32);

    if (g == 0) {
        size_t o = (size_t)d * HID_F + p * 4;
        float4 xv = *reinterpret_cast<const float4*>(x + o);
        float4 wv = *reinterpret_cast<const float4*>(dw + o);
        float s = DT * b[d];
        float4 r;
        r.x = ONE_MINUS_DT * xv.x + s * acc0 + C_NOISE * wv.x;
        r.y = ONE_MINUS_DT * xv.y + s * acc1 + C_NOISE * wv.y;
        r.z = ONE_MINUS_DT * xv.z + s * acc2 + C_NOISE * wv.z;
        r.w = ONE_MINUS_DT * xv.w + s * acc3 + C_NOISE * wv.w;
        *reinterpret_cast<float4*>(x + o) = r;
    }
}

extern "C" void kernel_launch(void* const* d_in, const int* in_sizes, int n_in,
                              void* d_out, int out_size, void* d_ws, size_t ws_size,
                              hipStream_t stream) {
    const float* h     = (const float*)d_in[0];
    const float* W_in  = (const float*)d_in[1];
    const float* W_msg = (const float*)d_in[2];
    const float* W_out = (const float*)d_in[3];
    const float* dW    = (const float*)d_in[4];
    const int*   src   = (const int*)d_in[5];
    const int*   dst   = (const int*)d_in[6];
    float* out = (float*)d_out;

    const size_t NH = (size_t)N_NODES * HID_F;  // 6.4M
    const int NBLK = (N_NODES + 255) / 256;     // 391

    float* x       = (float*)d_ws;              // 6.4M f
    bf16_t* m      = (bf16_t*)(x + NH);         // 6.4M bf16 (12.8 MB)
    float* a       = (float*)(m + NH);          // 100K f
    float* b       = a + N_NODES;               // 100K f
    int* deg_out_i = (int*)(b + N_NODES);       // 100K i
    int* deg_in_i  = deg_out_i + N_NODES;       // 100K i
    int* row_ptr   = deg_in_i + N_NODES;        // 100K+1 i
    int* cursor    = row_ptr + N_NODES + 1;     // 100K+1 i
    int* blocksum  = cursor + N_NODES + 1;      // 391 i
    int* blockpfx  = blocksum + 512;            // 391 i
    int* src_sorted= blockpfx + 512;            // 1.6M i

    // ---- one-time per launch: degrees, scales, CSR ----
    hipMemsetAsync(deg_out_i, 0, 2 * N_NODES * sizeof(int), stream);
    {
        dim3 ge((N_EDGES + 255) / 256);
        deg_kernel<<<ge, 256, 0, stream>>>(src, dst, deg_out_i, deg_in_i);
        scale_kernel<<<dim3(NBLK), 256, 0, stream>>>(deg_out_i, deg_in_i, a, b);
        scan_blocksum_kernel<<<dim3(NBLK), 256, 0, stream>>>(deg_in_i, blocksum);
        scan_top_kernel<<<1, 512, 0, stream>>>(blocksum, blockpfx, NBLK);
        scan_final_kernel<<<dim3(NBLK), 256, 0, stream>>>(deg_in_i, blockpfx, row_ptr, cursor);
        fill_kernel<<<ge, 256, 0, stream>>>(src, dst, cursor, src_sorted);
    }

    // ---- x = h @ W_in ----
    {
        const int nwaves = N_NODES / 16;                // 6250 (RPW=16)
        regw_mm_kernel<IN_F, HID_F, 16, false, false><<<dim3((nwaves + 3) / 4), 256, 0, stream>>>(
            h, W_in, x, nullptr, nwaves);
    }

    // ---- 10 Euler-Maruyama steps: m = bf16(a*(x@W_msg)); x = gather-update ----
    const int nwaves_msg = N_NODES / 8;                 // 12500 (RPW=8)
    const dim3 g_msg((nwaves_msg + 3) / 4);             // 3125
    const dim3 g_gather(N_NODES / 4);                   // 25000
    for (int k = 0; k < N_STEPS; k++) {
        regw_mm_kernel<HID_F, HID_F, 8, true, true><<<g_msg, 256, 0, stream>>>(
            x, W_msg, m, a, nwaves_msg);
        gather_update_kernel<<<g_gather, 256, 0, stream>>>(m, row_ptr, src_sorted, b, x,
                                                           dW + (size_t)k * NH);
    }

    // ---- out = x @ W_out ----
    {
        const int nwaves = N_NODES / 8;                 // 12500 (RPW=8)
        regw_mm_kernel<HID_F, OUT_F, 8, false, false><<<dim3((nwaves + 3) / 4), 256, 0, stream>>>(
            x, W_out, out, nullptr, nwaves);
    }
}

// Round 9
// 1015.153 us; speedup vs baseline: 1.2978x; 1.1796x over previous
//
#include <hip/hip_runtime.h>

#define N_NODES 100000
#define N_EDGES 1600000
#define IN_F 128
#define HID_F 64
#define OUT_F 40
#define N_STEPS 10

static constexpr float DT = 0.1f;
static constexpr float ONE_MINUS_DT = 0.9f;
// SIGMA * sqrt(DT) = 0.01 * sqrt(0.1)
static constexpr float C_NOISE = 0.0031622776601683794f;

typedef unsigned short bf16_t;
typedef __attribute__((ext_vector_type(8))) short bf16x8;  // MFMA A/B frag (4 VGPR)
typedef __attribute__((ext_vector_type(4))) float f32x4;   // MFMA C/D frag

// f32 -> bf16 round-to-nearest-even (finite values only)
static __device__ __forceinline__ bf16_t f2bf(float f) {
    union { float f; unsigned u; } v; v.f = f;
    unsigned r = v.u + 0x7fffu + ((v.u >> 16) & 1u);
    return (bf16_t)(r >> 16);
}
static __device__ __forceinline__ float bf2f(bf16_t h) {
    union { unsigned u; float f; } v; v.u = ((unsigned)h) << 16;
    return v.f;
}

// ---------------- f32 -> bf16 bulk convert (float4 / ushort4) ----------------
__global__ __launch_bounds__(256) void cvt_bf16_kernel(const float* __restrict__ in,
                                                       bf16_t* __restrict__ out, int n4) {
    int i = blockIdx.x * 256 + threadIdx.x;
    if (i < n4) {
        float4 v = reinterpret_cast<const float4*>(in)[i];
        ushort4 o;
        o.x = f2bf(v.x); o.y = f2bf(v.y); o.z = f2bf(v.z); o.w = f2bf(v.w);
        reinterpret_cast<ushort4*>(out)[i] = o;
    }
}

// ---------------- degree histograms (int) ----------------
__global__ __launch_bounds__(256) void deg_kernel(const int* __restrict__ src,
                                                  const int* __restrict__ dst,
                                                  int* __restrict__ deg_out,
                                                  int* __restrict__ deg_in) {
    int i = blockIdx.x * 256 + threadIdx.x;
    if (i < N_EDGES) {
        atomicAdd(&deg_out[src[i]], 1);
        atomicAdd(&deg_in[dst[i]], 1);
    }
}

// ---------------- per-node scale factors ----------------
__global__ __launch_bounds__(256) void scale_kernel(const int* __restrict__ deg_out,
                                                    const int* __restrict__ deg_in,
                                                    float* __restrict__ a,
                                                    float* __restrict__ b) {
    int i = blockIdx.x * 256 + threadIdx.x;
    if (i < N_NODES) {
        a[i] = rsqrtf((float)max(deg_out[i], 1));
        b[i] = rsqrtf((float)max(deg_in[i], 1));
    }
}

// ---------------- 3-kernel exclusive scan of deg_in -> row_ptr ----------------
__global__ __launch_bounds__(256) void scan_blocksum_kernel(const int* __restrict__ deg,
                                                            int* __restrict__ blocksum) {
    __shared__ int buf[256];
    int i = blockIdx.x * 256 + threadIdx.x;
    buf[threadIdx.x] = (i < N_NODES) ? deg[i] : 0;
    __syncthreads();
    for (int off = 128; off > 0; off >>= 1) {
        if (threadIdx.x < off) buf[threadIdx.x] += buf[threadIdx.x + off];
        __syncthreads();
    }
    if (threadIdx.x == 0) blocksum[blockIdx.x] = buf[0];
}

__global__ __launch_bounds__(512) void scan_top_kernel(const int* __restrict__ blocksum,
                                                       int* __restrict__ blockpfx,
                                                       int nblocks) {
    __shared__ int buf[512];
    int v = (threadIdx.x < nblocks) ? blocksum[threadIdx.x] : 0;
    buf[threadIdx.x] = v;
    __syncthreads();
    for (int off = 1; off < 512; off <<= 1) {
        int t = (threadIdx.x >= off) ? buf[threadIdx.x - off] : 0;
        __syncthreads();
        buf[threadIdx.x] += t;
        __syncthreads();
    }
    if (threadIdx.x < nblocks) blockpfx[threadIdx.x] = buf[threadIdx.x] - v;
}

__global__ __launch_bounds__(256) void scan_final_kernel(const int* __restrict__ deg,
                                                         const int* __restrict__ blockpfx,
                                                         int* __restrict__ row_ptr,
                                                         int* __restrict__ cursor) {
    __shared__ int buf[256];
    int i = blockIdx.x * 256 + threadIdx.x;
    int v = (i < N_NODES) ? deg[i] : 0;
    buf[threadIdx.x] = v;
    __syncthreads();
    for (int off = 1; off < 256; off <<= 1) {
        int t = (threadIdx.x >= off) ? buf[threadIdx.x - off] : 0;
        __syncthreads();
        buf[threadIdx.x] += t;
        __syncthreads();
    }
    int excl = blockpfx[blockIdx.x] + buf[threadIdx.x] - v;
    if (i < N_NODES) {
        row_ptr[i] = excl;
        cursor[i] = excl;
    }
    if (blockIdx.x == gridDim.x - 1 && threadIdx.x == 255)
        row_ptr[N_NODES] = blockpfx[blockIdx.x] + buf[255];
}

// ---------------- CSR fill: bucket edges by dst ----------------
__global__ __launch_bounds__(256) void fill_kernel(const int* __restrict__ src,
                                                   const int* __restrict__ dst,
                                                   int* __restrict__ cursor,
                                                   int* __restrict__ src_sorted) {
    int e = blockIdx.x * 256 + threadIdx.x;
    if (e < N_EDGES) {
        int pos = atomicAdd(&cursor[dst[e]], 1);
        src_sorted[pos] = src[e];
    }
}

// ---------------- MFMA row GEMM: Y[r,0..64) = (A_bf[r,K] @ W_bf[K,64]) * scale? ----
// 256 threads = 4 waves; wave = 32 rows x 64 cols via 16x16x32 bf16 MFMA.
// W staged in LDS; B-frags built once per wave (register-resident).
// A-frag: lane(l) row = l&15, k-chunk = (l>>4)*8 -> contiguous bf16x8 load.
// C/D: col = l&15 (+ct*16), row = (l>>4)*4 + i  [per cdna4 §3 verified mapping].
template <int K, bool SCALE, bool OUT_BF, bool OUT_F32>
__global__ __launch_bounds__(256) void mfma_mm_kernel(const bf16_t* __restrict__ A,
                                                      const bf16_t* __restrict__ Wb,
                                                      const float* __restrict__ scale,
                                                      bf16_t* __restrict__ Yb,
                                                      float* __restrict__ Yf) {
    __shared__ bf16_t wlds[K * HID_F];
    for (int i = threadIdx.x; i < K * HID_F / 2; i += 256)
        reinterpret_cast<unsigned*>(wlds)[i] = reinterpret_cast<const unsigned*>(Wb)[i];
    __syncthreads();

    const int lane = threadIdx.x & 63;
    const int wid = threadIdx.x >> 6;
    const int g = lane >> 4;   // 0..3 (k-group / row-group)
    const int c = lane & 15;   // 0..15 (row for A, col for B/C)
    const int rbase = blockIdx.x * 128 + wid * 32;
    if (rbase >= N_NODES) return;

    constexpr int KS = K / 32;

    bf16x8 bfrag[4][KS];
#pragma unroll
    for (int ct = 0; ct < 4; ct++)
#pragma unroll
        for (int ks = 0; ks < KS; ks++)
#pragma unroll
            for (int j = 0; j < 8; j++)
                bfrag[ct][ks][j] = (short)wlds[(ks * 32 + g * 8 + j) * HID_F + ct * 16 + c];

#pragma unroll
    for (int rt = 0; rt < 2; rt++) {
        const int r0 = rbase + rt * 16;

        bf16x8 afrag[KS];
#pragma unroll
        for (int ks = 0; ks < KS; ks++)
            afrag[ks] = *reinterpret_cast<const bf16x8*>(A + (size_t)(r0 + c) * K + ks * 32 + g * 8);

        float sc[4];
        if (SCALE) {
#pragma unroll
            for (int i = 0; i < 4; i++) sc[i] = scale[r0 + g * 4 + i];
        }

#pragma unroll
        for (int ct = 0; ct < 4; ct++) {
            f32x4 acc = {0.f, 0.f, 0.f, 0.f};
#pragma unroll
            for (int ks = 0; ks < KS; ks++)
                acc = __builtin_amdgcn_mfma_f32_16x16x32_bf16(afrag[ks], bfrag[ct][ks], acc, 0, 0, 0);
#pragma unroll
            for (int i = 0; i < 4; i++) {
                int row = r0 + g * 4 + i;
                float v = SCALE ? acc[i] * sc[i] : acc[i];
                size_t o = (size_t)row * HID_F + ct * 16 + c;
                if (OUT_BF) Yb[o] = f2bf(v);
                if (OUT_F32) Yf[o] = v;
            }
        }
    }
}

// ---------------- fused gather + Euler-Maruyama update (bf16 m) ----------------
// One wave per dst node. 4 edges concurrently: 16-lane group g takes edge jj+g,
// each lane loads ushort4 (8B) = 4 features at p=lane&15. shfl_xor reduce,
// then 16-lane float4 update of x (+ bf16 copy for the next MFMA step).
template <bool WRITE_BF>
__global__ __launch_bounds__(256) void gather_update_kernel(const bf16_t* __restrict__ m,
                                                            const int* __restrict__ row_ptr,
                                                            const int* __restrict__ src_sorted,
                                                            const float* __restrict__ b,
                                                            float* __restrict__ x,
                                                            bf16_t* __restrict__ xb,
                                                            const float* __restrict__ dw) {
    int d = blockIdx.x * 4 + (threadIdx.x >> 6);
    int lane = threadIdx.x & 63;
    int g = lane >> 4;
    int p = lane & 15;

    int beg = row_ptr[d];
    int end = row_ptr[d + 1];

    float acc0 = 0.f, acc1 = 0.f, acc2 = 0.f, acc3 = 0.f;
    int j = beg;
    while (j < end) {
        int cnt = min(end - j, 64);
        int idx = (lane < cnt) ? src_sorted[j + lane] : 0;
#pragma unroll 2
        for (int jj = 0; jj < cnt; jj += 4) {
            int e = jj + g;
            int s = __shfl(idx, min(e, cnt - 1));
            if (e < cnt) {
                ushort4 mv = *reinterpret_cast<const ushort4*>(m + (size_t)s * HID_F + p * 4);
                acc0 += bf2f(mv.x);
                acc1 += bf2f(mv.y);
                acc2 += bf2f(mv.z);
                acc3 += bf2f(mv.w);
            }
        }
        j += cnt;
    }

    acc0 += __shfl_xor(acc0, 16);
    acc1 += __shfl_xor(acc1, 16);
    acc2 += __shfl_xor(acc2, 16);
    acc3 += __shfl_xor(acc3, 16);
    acc0 += __shfl_xor(acc0, 32);
    acc1 += __shfl_xor(acc1, 32);
    acc2 += __shfl_xor(acc2, 32);
    acc3 += __shfl_xor(acc3, 32);

    if (g == 0) {
        size_t o = (size_t)d * HID_F + p * 4;
        float4 xv = *reinterpret_cast<const float4*>(x + o);
        float4 wv = *reinterpret_cast<const float4*>(dw + o);
        float s = DT * b[d];
        float4 r;
        r.x = ONE_MINUS_DT * xv.x + s * acc0 + C_NOISE * wv.x;
        r.y = ONE_MINUS_DT * xv.y + s * acc1 + C_NOISE * wv.y;
        r.z = ONE_MINUS_DT * xv.z + s * acc2 + C_NOISE * wv.z;
        r.w = ONE_MINUS_DT * xv.w + s * acc3 + C_NOISE * wv.w;
        *reinterpret_cast<float4*>(x + o) = r;
        if (WRITE_BF) {
            ushort4 rb;
            rb.x = f2bf(r.x); rb.y = f2bf(r.y); rb.z = f2bf(r.z); rb.w = f2bf(r.w);
            *reinterpret_cast<ushort4*>(xb + o) = rb;
        }
    }
}

// ---------------- out projection (f32 regw): out[n,40] = x[n,64] @ W_out[64,40] ----
template <int K, int NCOL, int RPW>
__global__ __launch_bounds__(256) void regw_mm_kernel(const float* __restrict__ A,
                                                      const float* __restrict__ W,
                                                      float* __restrict__ Y,
                                                      int nwaves) {
    int lane = threadIdx.x & 63;
    int wid = __builtin_amdgcn_readfirstlane((blockIdx.x * 256 + threadIdx.x) >> 6);
    if (wid >= nwaves) return;

    float wreg[K];
#pragma unroll
    for (int k = 0; k < K; k++)
        wreg[k] = (lane < NCOL) ? W[k * NCOL + lane] : 0.0f;

    int r0 = wid * RPW;
#pragma unroll 1
    for (int rr = 0; rr < RPW; rr += 4) {
        int r = r0 + rr;
        const float* a0 = A + (size_t)(r + 0) * K;
        const float* a1 = A + (size_t)(r + 1) * K;
        const float* a2 = A + (size_t)(r + 2) * K;
        const float* a3 = A + (size_t)(r + 3) * K;
        float acc0 = 0.f, acc1 = 0.f, acc2 = 0.f, acc3 = 0.f;
#pragma unroll
        for (int k = 0; k < K; k++) {
            float w = wreg[k];
            acc0 = fmaf(a0[k], w, acc0);
            acc1 = fmaf(a1[k], w, acc1);
            acc2 = fmaf(a2[k], w, acc2);
            acc3 = fmaf(a3[k], w, acc3);
        }
        if (lane < NCOL) {
            Y[(size_t)(r + 0) * NCOL + lane] = acc0;
            Y[(size_t)(r + 1) * NCOL + lane] = acc1;
            Y[(size_t)(r + 2) * NCOL + lane] = acc2;
            Y[(size_t)(r + 3) * NCOL + lane] = acc3;
        }
    }
}

extern "C" void kernel_launch(void* const* d_in, const int* in_sizes, int n_in,
                              void* d_out, int out_size, void* d_ws, size_t ws_size,
                              hipStream_t stream) {
    const float* h     = (const float*)d_in[0];
    const float* W_in  = (const float*)d_in[1];
    const float* W_msg = (const float*)d_in[2];
    const float* W_out = (const float*)d_in[3];
    const float* dW    = (const float*)d_in[4];
    const int*   src   = (const int*)d_in[5];
    const int*   dst   = (const int*)d_in[6];
    float* out = (float*)d_out;

    const size_t NH = (size_t)N_NODES * HID_F;  // 6.4M
    const int NBLK = (N_NODES + 255) / 256;     // 391

    float*  x       = (float*)d_ws;                          // 6.4M f32
    bf16_t* m       = (bf16_t*)(x + NH);                     // 6.4M bf16
    bf16_t* x_bf    = m + NH;                                // 6.4M bf16
    bf16_t* h_bf    = x_bf + NH;                             // 12.8M bf16
    bf16_t* Win_bf  = h_bf + (size_t)N_NODES * IN_F;         // 8192 bf16
    bf16_t* Wmsg_bf = Win_bf + IN_F * HID_F;                 // 4096 bf16
    float*  a       = (float*)(Wmsg_bf + HID_F * HID_F);     // 100K f
    float*  b       = a + N_NODES;                           // 100K f
    int* deg_out_i  = (int*)(b + N_NODES);                   // 100K i
    int* deg_in_i   = deg_out_i + N_NODES;                   // 100K i
    int* row_ptr    = deg_in_i + N_NODES;                    // 100K+1 i
    int* cursor     = row_ptr + N_NODES + 1;                 // 100K+1 i
    int* blocksum   = cursor + N_NODES + 1;                  // 391 i
    int* blockpfx   = blocksum + 512;                        // 391 i
    int* src_sorted = blockpfx + 512;                        // 1.6M i

    // ---- one-time: bf16 conversions of h, W_in, W_msg ----
    cvt_bf16_kernel<<<dim3((N_NODES * IN_F / 4 + 255) / 256), 256, 0, stream>>>(
        h, h_bf, N_NODES * IN_F / 4);
    cvt_bf16_kernel<<<dim3((IN_F * HID_F / 4 + 255) / 256), 256, 0, stream>>>(
        W_in, Win_bf, IN_F * HID_F / 4);
    cvt_bf16_kernel<<<dim3((HID_F * HID_F / 4 + 255) / 256), 256, 0, stream>>>(
        W_msg, Wmsg_bf, HID_F * HID_F / 4);

    // ---- one-time: degrees, scales, CSR ----
    hipMemsetAsync(deg_out_i, 0, 2 * N_NODES * sizeof(int), stream);
    {
        dim3 ge((N_EDGES + 255) / 256);
        deg_kernel<<<ge, 256, 0, stream>>>(src, dst, deg_out_i, deg_in_i);
        scale_kernel<<<dim3(NBLK), 256, 0, stream>>>(deg_out_i, deg_in_i, a, b);
        scan_blocksum_kernel<<<dim3(NBLK), 256, 0, stream>>>(deg_in_i, blocksum);
        scan_top_kernel<<<1, 512, 0, stream>>>(blocksum, blockpfx, NBLK);
        scan_final_kernel<<<dim3(NBLK), 256, 0, stream>>>(deg_in_i, blockpfx, row_ptr, cursor);
        fill_kernel<<<ge, 256, 0, stream>>>(src, dst, cursor, src_sorted);
    }

    const dim3 g_mfma((N_NODES + 127) / 128);  // 782

    // ---- x = h @ W_in  (f32 + bf16 copy) ----
    mfma_mm_kernel<IN_F, false, true, true><<<g_mfma, 256, 0, stream>>>(
        h_bf, Win_bf, nullptr, x_bf, x);

    // ---- 10 Euler-Maruyama steps ----
    const dim3 g_gather(N_NODES / 4);  // 25000
    for (int k = 0; k < N_STEPS; k++) {
        // m = bf16( a * (x_bf @ W_msg_bf) )
        mfma_mm_kernel<HID_F, true, true, false><<<g_mfma, 256, 0, stream>>>(
            x_bf, Wmsg_bf, a, m, nullptr);
        // x = 0.9 x + 0.1 b * gather(m) + C_NOISE dW_k ; x_bf = bf16(x) except last
        const float* dwk = dW + (size_t)k * NH;
        if (k < N_STEPS - 1)
            gather_update_kernel<true><<<g_gather, 256, 0, stream>>>(
                m, row_ptr, src_sorted, b, x, x_bf, dwk);
        else
            gather_update_kernel<false><<<g_gather, 256, 0, stream>>>(
                m, row_ptr, src_sorted, b, x, x_bf, dwk);
    }

    // ---- out = x @ W_out ----
    {
        const int nwaves = N_NODES / 8;  // 12500
        regw_mm_kernel<HID_F, OUT_F, 8><<<dim3((nwaves + 3) / 4), 256, 0, stream>>>(
            x, W_out, out, nwaves);
    }
}

// Round 10
// 952.637 us; speedup vs baseline: 1.3830x; 1.0656x over previous
//
#include <hip/hip_runtime.h>

#define N_NODES 100000
#define N_EDGES 1600000
#define IN_F 128
#define HID_F 64
#define OUT_F 40
#define N_STEPS 10

static constexpr float DT = 0.1f;
static constexpr float ONE_MINUS_DT = 0.9f;
// SIGMA * sqrt(DT) = 0.01 * sqrt(0.1)
static constexpr float C_NOISE = 0.0031622776601683794f;

typedef unsigned short bf16_t;
typedef __attribute__((ext_vector_type(8))) short bf16x8;  // MFMA A/B frag (4 VGPR)
typedef __attribute__((ext_vector_type(4))) float f32x4;   // MFMA C/D frag

// f32 -> bf16 round-to-nearest-even (finite values only)
static __device__ __forceinline__ bf16_t f2bf(float f) {
    union { float f; unsigned u; } v; v.f = f;
    unsigned r = v.u + 0x7fffu + ((v.u >> 16) & 1u);
    return (bf16_t)(r >> 16);
}
// packed f32x2 -> bf16x2 (RNE) — single HW instr on gfx950
static __device__ __forceinline__ unsigned cvt_pk_bf16(float lo, float hi) {
    unsigned r;
    asm("v_cvt_pk_bf16_f32 %0, %1, %2" : "=v"(r) : "v"(lo), "v"(hi));
    return r;
}
static __device__ __forceinline__ float lo16f(unsigned u) {
    union { unsigned u; float f; } v; v.u = u << 16; return v.f;
}
static __device__ __forceinline__ float hi16f(unsigned u) {
    union { unsigned u; float f; } v; v.u = u & 0xffff0000u; return v.f;
}

// ---------------- W[K x NCOL] f32 -> Wt[NCOL x K] bf16 (tiny, once) ----------------
__global__ __launch_bounds__(256) void transpose_w_kernel(const float* __restrict__ W,
                                                          bf16_t* __restrict__ Wt,
                                                          int K, int NCOL) {
    int i = blockIdx.x * 256 + threadIdx.x;
    if (i < K * NCOL) {
        int k = i / NCOL, c = i - k * NCOL;
        Wt[c * K + k] = f2bf(W[i]);
    }
}

// ---------------- degree histograms (int) ----------------
__global__ __launch_bounds__(256) void deg_kernel(const int* __restrict__ src,
                                                  const int* __restrict__ dst,
                                                  int* __restrict__ deg_out,
                                                  int* __restrict__ deg_in) {
    int i = blockIdx.x * 256 + threadIdx.x;
    if (i < N_EDGES) {
        atomicAdd(&deg_out[src[i]], 1);
        atomicAdd(&deg_in[dst[i]], 1);
    }
}

// ---------------- per-node scale factors ----------------
__global__ __launch_bounds__(256) void scale_kernel(const int* __restrict__ deg_out,
                                                    const int* __restrict__ deg_in,
                                                    float* __restrict__ a,
                                                    float* __restrict__ b) {
    int i = blockIdx.x * 256 + threadIdx.x;
    if (i < N_NODES) {
        a[i] = rsqrtf((float)max(deg_out[i], 1));
        b[i] = rsqrtf((float)max(deg_in[i], 1));
    }
}

// ---------------- 3-kernel exclusive scan of deg_in -> row_ptr ----------------
__global__ __launch_bounds__(256) void scan_blocksum_kernel(const int* __restrict__ deg,
                                                            int* __restrict__ blocksum) {
    __shared__ int buf[256];
    int i = blockIdx.x * 256 + threadIdx.x;
    buf[threadIdx.x] = (i < N_NODES) ? deg[i] : 0;
    __syncthreads();
    for (int off = 128; off > 0; off >>= 1) {
        if (threadIdx.x < off) buf[threadIdx.x] += buf[threadIdx.x + off];
        __syncthreads();
    }
    if (threadIdx.x == 0) blocksum[blockIdx.x] = buf[0];
}

__global__ __launch_bounds__(512) void scan_top_kernel(const int* __restrict__ blocksum,
                                                       int* __restrict__ blockpfx,
                                                       int nblocks) {
    __shared__ int buf[512];
    int v = (threadIdx.x < nblocks) ? blocksum[threadIdx.x] : 0;
    buf[threadIdx.x] = v;
    __syncthreads();
    for (int off = 1; off < 512; off <<= 1) {
        int t = (threadIdx.x >= off) ? buf[threadIdx.x - off] : 0;
        __syncthreads();
        buf[threadIdx.x] += t;
        __syncthreads();
    }
    if (threadIdx.x < nblocks) blockpfx[threadIdx.x] = buf[threadIdx.x] - v;
}

__global__ __launch_bounds__(256) void scan_final_kernel(const int* __restrict__ deg,
                                                         const int* __restrict__ blockpfx,
                                                         int* __restrict__ row_ptr,
                                                         int* __restrict__ cursor) {
    __shared__ int buf[256];
    int i = blockIdx.x * 256 + threadIdx.x;
    int v = (i < N_NODES) ? deg[i] : 0;
    buf[threadIdx.x] = v;
    __syncthreads();
    for (int off = 1; off < 256; off <<= 1) {
        int t = (threadIdx.x >= off) ? buf[threadIdx.x - off] : 0;
        __syncthreads();
        buf[threadIdx.x] += t;
        __syncthreads();
    }
    int excl = blockpfx[blockIdx.x] + buf[threadIdx.x] - v;
    if (i < N_NODES) {
        row_ptr[i] = excl;
        cursor[i] = excl;
    }
    if (blockIdx.x == gridDim.x - 1 && threadIdx.x == 255)
        row_ptr[N_NODES] = blockpfx[blockIdx.x] + buf[255];
}

// ---------------- CSR fill: bucket edges by dst ----------------
__global__ __launch_bounds__(256) void fill_kernel(const int* __restrict__ src,
                                                   const int* __restrict__ dst,
                                                   int* __restrict__ cursor,
                                                   int* __restrict__ src_sorted) {
    int e = blockIdx.x * 256 + threadIdx.x;
    if (e < N_EDGES) {
        int pos = atomicAdd(&cursor[dst[e]], 1);
        src_sorted[pos] = src[e];
    }
}

// ---------------- MFMA row GEMM: Y[r,0..64) = (A_f32[r,K] @ W[K,64]) * scale? ----
// 256 threads = 4 waves; wave = 32 rows x 64 cols via 16x16x32 bf16 MFMA.
// B-frags: one bf16x8 load each from pre-transposed Wt[col][k] in global (L2-hot).
// A-frags: f32 loads converted in-register via v_cvt_pk_bf16_f32.
// No LDS, no barriers.
template <int K, bool SCALE, bool OUT_BF, bool OUT_F32>
__global__ __launch_bounds__(256) void mfma_mm_kernel(const float* __restrict__ A,
                                                      const bf16_t* __restrict__ Wt,
                                                      const float* __restrict__ scale,
                                                      bf16_t* __restrict__ Yb,
                                                      float* __restrict__ Yf) {
    const int lane = threadIdx.x & 63;
    const int wid = threadIdx.x >> 6;
    const int g = lane >> 4;   // 0..3
    const int c = lane & 15;   // 0..15
    const int rbase = blockIdx.x * 128 + wid * 32;
    if (rbase >= N_NODES) return;

    constexpr int KS = K / 32;
    union frag_u { unsigned u[4]; bf16x8 v; };

    bf16x8 bfrag[4][KS];
#pragma unroll
    for (int ct = 0; ct < 4; ct++)
#pragma unroll
        for (int ks = 0; ks < KS; ks++)
            bfrag[ct][ks] = *reinterpret_cast<const bf16x8*>(
                Wt + (size_t)(ct * 16 + c) * K + ks * 32 + g * 8);

#pragma unroll
    for (int rt = 0; rt < 2; rt++) {
        const int r0 = rbase + rt * 16;

        bf16x8 afrag[KS];
#pragma unroll
        for (int ks = 0; ks < KS; ks++) {
            const float* ap = A + (size_t)(r0 + c) * K + ks * 32 + g * 8;
            float4 a0 = *reinterpret_cast<const float4*>(ap);
            float4 a1 = *reinterpret_cast<const float4*>(ap + 4);
            frag_u f;
            f.u[0] = cvt_pk_bf16(a0.x, a0.y);
            f.u[1] = cvt_pk_bf16(a0.z, a0.w);
            f.u[2] = cvt_pk_bf16(a1.x, a1.y);
            f.u[3] = cvt_pk_bf16(a1.z, a1.w);
            afrag[ks] = f.v;
        }

        float sc[4];
        if (SCALE) {
#pragma unroll
            for (int i = 0; i < 4; i++) sc[i] = scale[r0 + g * 4 + i];
        }

#pragma unroll
        for (int ct = 0; ct < 4; ct++) {
            f32x4 acc = {0.f, 0.f, 0.f, 0.f};
#pragma unroll
            for (int ks = 0; ks < KS; ks++)
                acc = __builtin_amdgcn_mfma_f32_16x16x32_bf16(afrag[ks], bfrag[ct][ks], acc, 0, 0, 0);
#pragma unroll
            for (int i = 0; i < 4; i++) {
                int row = r0 + g * 4 + i;
                float v = SCALE ? acc[i] * sc[i] : acc[i];
                size_t o = (size_t)row * HID_F + ct * 16 + c;
                if (OUT_BF) Yb[o] = f2bf(v);
                if (OUT_F32) Yf[o] = v;
            }
        }
    }
}

// ---------------- fused gather + Euler-Maruyama update (bf16 m) ----------------
// One wave per dst node. 8 edges in flight: 8-lane group g takes edge jj+g,
// each lane loads dwordx4 (16B = 8 bf16 features at p=lane&7). 3-step shfl_xor
// reduce, then 8-lane 2x float4 update of x.
__global__ __launch_bounds__(256) void gather_update_kernel(const bf16_t* __restrict__ m,
                                                            const int* __restrict__ row_ptr,
                                                            const int* __restrict__ src_sorted,
                                                            const float* __restrict__ b,
                                                            float* __restrict__ x,
                                                            const float* __restrict__ dw) {
    int d = blockIdx.x * 4 + (threadIdx.x >> 6);
    int lane = threadIdx.x & 63;
    int g = lane >> 3;   // edge slot 0..7
    int p = lane & 7;    // feature octet: features [p*8, p*8+8)

    int beg = row_ptr[d];
    int end = row_ptr[d + 1];

    float acc[8];
#pragma unroll
    for (int i = 0; i < 8; i++) acc[i] = 0.f;

    for (int j = beg; j < end; j += 64) {
        int cnt = min(end - j, 64);
        int idx = (lane < cnt) ? src_sorted[j + lane] : 0;
#pragma unroll 4
        for (int jj = 0; jj < cnt; jj += 8) {
            int e = jj + g;
            int s = __shfl(idx, min(e, cnt - 1));
            if (e < cnt) {
                uint4 mv = *reinterpret_cast<const uint4*>(m + (size_t)s * HID_F + p * 8);
                acc[0] += lo16f(mv.x); acc[1] += hi16f(mv.x);
                acc[2] += lo16f(mv.y); acc[3] += hi16f(mv.y);
                acc[4] += lo16f(mv.z); acc[5] += hi16f(mv.z);
                acc[6] += lo16f(mv.w); acc[7] += hi16f(mv.w);
            }
        }
    }

#pragma unroll
    for (int i = 0; i < 8; i++) {
        acc[i] += __shfl_xor(acc[i], 8);
        acc[i] += __shfl_xor(acc[i], 16);
        acc[i] += __shfl_xor(acc[i], 32);
    }

    if (g == 0) {
        size_t o = (size_t)d * HID_F + p * 8;
        float4 x0 = *reinterpret_cast<const float4*>(x + o);
        float4 x1 = *reinterpret_cast<const float4*>(x + o + 4);
        float4 w0 = *reinterpret_cast<const float4*>(dw + o);
        float4 w1 = *reinterpret_cast<const float4*>(dw + o + 4);
        float s = DT * b[d];
        float4 r0, r1;
        r0.x = ONE_MINUS_DT * x0.x + s * acc[0] + C_NOISE * w0.x;
        r0.y = ONE_MINUS_DT * x0.y + s * acc[1] + C_NOISE * w0.y;
        r0.z = ONE_MINUS_DT * x0.z + s * acc[2] + C_NOISE * w0.z;
        r0.w = ONE_MINUS_DT * x0.w + s * acc[3] + C_NOISE * w0.w;
        r1.x = ONE_MINUS_DT * x1.x + s * acc[4] + C_NOISE * w1.x;
        r1.y = ONE_MINUS_DT * x1.y + s * acc[5] + C_NOISE * w1.y;
        r1.z = ONE_MINUS_DT * x1.z + s * acc[6] + C_NOISE * w1.z;
        r1.w = ONE_MINUS_DT * x1.w + s * acc[7] + C_NOISE * w1.w;
        *reinterpret_cast<float4*>(x + o) = r0;
        *reinterpret_cast<float4*>(x + o + 4) = r1;
    }
}

// ---------------- out projection (f32 regw): out[n,40] = x[n,64] @ W_out[64,40] ----
template <int K, int NCOL, int RPW>
__global__ __launch_bounds__(256) void regw_mm_kernel(const float* __restrict__ A,
                                                      const float* __restrict__ W,
                                                      float* __restrict__ Y,
                                                      int nwaves) {
    int lane = threadIdx.x & 63;
    int wid = __builtin_amdgcn_readfirstlane((blockIdx.x * 256 + threadIdx.x) >> 6);
    if (wid >= nwaves) return;

    float wreg[K];
#pragma unroll
    for (int k = 0; k < K; k++)
        wreg[k] = (lane < NCOL) ? W[k * NCOL + lane] : 0.0f;

    int r0 = wid * RPW;
#pragma unroll 1
    for (int rr = 0; rr < RPW; rr += 4) {
        int r = r0 + rr;
        const float* a0 = A + (size_t)(r + 0) * K;
        const float* a1 = A + (size_t)(r + 1) * K;
        const float* a2 = A + (size_t)(r + 2) * K;
        const float* a3 = A + (size_t)(r + 3) * K;
        float acc0 = 0.f, acc1 = 0.f, acc2 = 0.f, acc3 = 0.f;
#pragma unroll
        for (int k = 0; k < K; k++) {
            float w = wreg[k];
            acc0 = fmaf(a0[k], w, acc0);
            acc1 = fmaf(a1[k], w, acc1);
            acc2 = fmaf(a2[k], w, acc2);
            acc3 = fmaf(a3[k], w, acc3);
        }
        if (lane < NCOL) {
            Y[(size_t)(r + 0) * NCOL + lane] = acc0;
            Y[(size_t)(r + 1) * NCOL + lane] = acc1;
            Y[(size_t)(r + 2) * NCOL + lane] = acc2;
            Y[(size_t)(r + 3) * NCOL + lane] = acc3;
        }
    }
}

extern "C" void kernel_launch(void* const* d_in, const int* in_sizes, int n_in,
                              void* d_out, int out_size, void* d_ws, size_t ws_size,
                              hipStream_t stream) {
    const float* h     = (const float*)d_in[0];
    const float* W_in  = (const float*)d_in[1];
    const float* W_msg = (const float*)d_in[2];
    const float* W_out = (const float*)d_in[3];
    const float* dW    = (const float*)d_in[4];
    const int*   src   = (const int*)d_in[5];
    const int*   dst   = (const int*)d_in[6];
    float* out = (float*)d_out;

    const size_t NH = (size_t)N_NODES * HID_F;  // 6.4M
    const int NBLK = (N_NODES + 255) / 256;     // 391

    float*  x       = (float*)d_ws;                          // 6.4M f32
    bf16_t* m       = (bf16_t*)(x + NH);                     // 6.4M bf16
    bf16_t* Win_t   = m + NH;                                // 8192 bf16 (64 x 128)
    bf16_t* Wmsg_t  = Win_t + IN_F * HID_F;                  // 4096 bf16 (64 x 64)
    float*  a       = (float*)(Wmsg_t + HID_F * HID_F);      // 100K f
    float*  b       = a + N_NODES;                           // 100K f
    int* deg_out_i  = (int*)(b + N_NODES);                   // 100K i
    int* deg_in_i   = deg_out_i + N_NODES;                   // 100K i
    int* row_ptr    = deg_in_i + N_NODES;                    // 100K+1 i
    int* cursor     = row_ptr + N_NODES + 1;                 // 100K+1 i
    int* blocksum   = cursor + N_NODES + 1;                  // 391 i
    int* blockpfx   = blocksum + 512;                        // 391 i
    int* src_sorted = blockpfx + 512;                        // 1.6M i

    // ---- one-time: transposed bf16 weights ----
    transpose_w_kernel<<<dim3((IN_F * HID_F + 255) / 256), 256, 0, stream>>>(
        W_in, Win_t, IN_F, HID_F);
    transpose_w_kernel<<<dim3((HID_F * HID_F + 255) / 256), 256, 0, stream>>>(
        W_msg, Wmsg_t, HID_F, HID_F);

    // ---- one-time: degrees, scales, CSR ----
    hipMemsetAsync(deg_out_i, 0, 2 * N_NODES * sizeof(int), stream);
    {
        dim3 ge((N_EDGES + 255) / 256);
        deg_kernel<<<ge, 256, 0, stream>>>(src, dst, deg_out_i, deg_in_i);
        scale_kernel<<<dim3(NBLK), 256, 0, stream>>>(deg_out_i, deg_in_i, a, b);
        scan_blocksum_kernel<<<dim3(NBLK), 256, 0, stream>>>(deg_in_i, blocksum);
        scan_top_kernel<<<1, 512, 0, stream>>>(blocksum, blockpfx, NBLK);
        scan_final_kernel<<<dim3(NBLK), 256, 0, stream>>>(deg_in_i, blockpfx, row_ptr, cursor);
        fill_kernel<<<ge, 256, 0, stream>>>(src, dst, cursor, src_sorted);
    }

    const dim3 g_mfma((N_NODES + 127) / 128);  // 782

    // ---- x = h @ W_in (f32 out) ----
    mfma_mm_kernel<IN_F, false, false, true><<<g_mfma, 256, 0, stream>>>(
        h, Win_t, nullptr, nullptr, x);

    // ---- 10 Euler-Maruyama steps ----
    const dim3 g_gather(N_NODES / 4);  // 25000
    for (int k = 0; k < N_STEPS; k++) {
        // m = bf16( a * (x @ W_msg) )   (A = f32 x, converted in-register)
        mfma_mm_kernel<HID_F, true, true, false><<<g_mfma, 256, 0, stream>>>(
            x, Wmsg_t, a, m, nullptr);
        // x = 0.9 x + 0.1 b * gather(m) + C_NOISE dW_k
        gather_update_kernel<<<g_gather, 256, 0, stream>>>(
            m, row_ptr, src_sorted, b, x, dW + (size_t)k * NH);
    }

    // ---- out = x @ W_out ----
    {
        const int nwaves = N_NODES / 8;  // 12500
        regw_mm_kernel<HID_F, OUT_F, 8><<<dim3((nwaves + 3) / 4), 256, 0, stream>>>(
            x, W_out, out, nwaves);
    }
}

// Round 12
// 941.886 us; speedup vs baseline: 1.3987x; 1.0114x over previous
//
#include <hip/hip_runtime.h>

#define N_NODES 100000
#define N_EDGES 1600000
#define IN_F 128
#define HID_F 64
#define OUT_F 40
#define N_STEPS 10

static constexpr float DT = 0.1f;
static constexpr float ONE_MINUS_DT = 0.9f;
// SIGMA * sqrt(DT) = 0.01 * sqrt(0.1)
static constexpr float C_NOISE = 0.0031622776601683794f;

typedef unsigned short bf16_t;
typedef unsigned char fp8_t;
typedef __attribute__((ext_vector_type(8))) short bf16x8;  // MFMA A/B frag (4 VGPR)
typedef __attribute__((ext_vector_type(4))) float f32x4;   // MFMA C/D frag
typedef __attribute__((ext_vector_type(2))) float f32x2;

// f32 -> bf16 round-to-nearest-even (finite values only)
static __device__ __forceinline__ bf16_t f2bf(float f) {
    union { float f; unsigned u; } v; v.f = f;
    unsigned r = v.u + 0x7fffu + ((v.u >> 16) & 1u);
    return (bf16_t)(r >> 16);
}
// packed f32x2 -> bf16x2 (RNE) — single HW instr on gfx950
static __device__ __forceinline__ unsigned cvt_pk_bf16(float lo, float hi) {
    unsigned r;
    asm("v_cvt_pk_bf16_f32 %0, %1, %2" : "=v"(r) : "v"(lo), "v"(hi));
    return r;
}
// f32 -> fp8 e4m3 (OCP on gfx950), single value via HW pack
static __device__ __forceinline__ fp8_t f32_to_fp8(float v) {
    int r = __builtin_amdgcn_cvt_pk_fp8_f32(v, v, 0, false);
    return (fp8_t)(r & 0xff);
}
// 2 fp8 (word-select WS within dword) -> 2 f32, HW unpack. WS must be literal.
template <bool HI>
static __device__ __forceinline__ f32x2 fp8x2_to_f32(unsigned w) {
    return __builtin_amdgcn_cvt_pk_f32_fp8((int)w, HI);
}

// ---------------- W[K x NCOL] f32 -> Wt[NCOL x K] bf16 (tiny, once) ----------------
__global__ __launch_bounds__(256) void transpose_w_kernel(const float* __restrict__ W,
                                                          bf16_t* __restrict__ Wt,
                                                          int K, int NCOL) {
    int i = blockIdx.x * 256 + threadIdx.x;
    if (i < K * NCOL) {
        int k = i / NCOL, c = i - k * NCOL;
        Wt[c * K + k] = f2bf(W[i]);
    }
}

// ---------------- degree histograms (int) ----------------
__global__ __launch_bounds__(256) void deg_kernel(const int* __restrict__ src,
                                                  const int* __restrict__ dst,
                                                  int* __restrict__ deg_out,
                                                  int* __restrict__ deg_in) {
    int i = blockIdx.x * 256 + threadIdx.x;
    if (i < N_EDGES) {
        atomicAdd(&deg_out[src[i]], 1);
        atomicAdd(&deg_in[dst[i]], 1);
    }
}

// ---------------- per-node scale factors ----------------
__global__ __launch_bounds__(256) void scale_kernel(const int* __restrict__ deg_out,
                                                    const int* __restrict__ deg_in,
                                                    float* __restrict__ a,
                                                    float* __restrict__ b) {
    int i = blockIdx.x * 256 + threadIdx.x;
    if (i < N_NODES) {
        a[i] = rsqrtf((float)max(deg_out[i], 1));
        b[i] = rsqrtf((float)max(deg_in[i], 1));
    }
}

// ---------------- 3-kernel exclusive scan of deg_in -> row_ptr ----------------
__global__ __launch_bounds__(256) void scan_blocksum_kernel(const int* __restrict__ deg,
                                                            int* __restrict__ blocksum) {
    __shared__ int buf[256];
    int i = blockIdx.x * 256 + threadIdx.x;
    buf[threadIdx.x] = (i < N_NODES) ? deg[i] : 0;
    __syncthreads();
    for (int off = 128; off > 0; off >>= 1) {
        if (threadIdx.x < off) buf[threadIdx.x] += buf[threadIdx.x + off];
        __syncthreads();
    }
    if (threadIdx.x == 0) blocksum[blockIdx.x] = buf[0];
}

__global__ __launch_bounds__(512) void scan_top_kernel(const int* __restrict__ blocksum,
                                                       int* __restrict__ blockpfx,
                                                       int nblocks) {
    __shared__ int buf[512];
    int v = (threadIdx.x < nblocks) ? blocksum[threadIdx.x] : 0;
    buf[threadIdx.x] = v;
    __syncthreads();
    for (int off = 1; off < 512; off <<= 1) {
        int t = (threadIdx.x >= off) ? buf[threadIdx.x - off] : 0;
        __syncthreads();
        buf[threadIdx.x] += t;
        __syncthreads();
    }
    if (threadIdx.x < nblocks) blockpfx[threadIdx.x] = buf[threadIdx.x] - v;
}

__global__ __launch_bounds__(256) void scan_final_kernel(const int* __restrict__ deg,
                                                         const int* __restrict__ blockpfx,
                                                         int* __restrict__ row_ptr,
                                                         int* __restrict__ cursor) {
    __shared__ int buf[256];
    int i = blockIdx.x * 256 + threadIdx.x;
    int v = (i < N_NODES) ? deg[i] : 0;
    buf[threadIdx.x] = v;
    __syncthreads();
    for (int off = 1; off < 256; off <<= 1) {
        int t = (threadIdx.x >= off) ? buf[threadIdx.x - off] : 0;
        __syncthreads();
        buf[threadIdx.x] += t;
        __syncthreads();
    }
    int excl = blockpfx[blockIdx.x] + buf[threadIdx.x] - v;
    if (i < N_NODES) {
        row_ptr[i] = excl;
        cursor[i] = excl;
    }
    if (blockIdx.x == gridDim.x - 1 && threadIdx.x == 255)
        row_ptr[N_NODES] = blockpfx[blockIdx.x] + buf[255];
}

// ---------------- CSR fill: bucket edges by dst ----------------
__global__ __launch_bounds__(256) void fill_kernel(const int* __restrict__ src,
                                                   const int* __restrict__ dst,
                                                   int* __restrict__ cursor,
                                                   int* __restrict__ src_sorted) {
    int e = blockIdx.x * 256 + threadIdx.x;
    if (e < N_EDGES) {
        int pos = atomicAdd(&cursor[dst[e]], 1);
        src_sorted[pos] = src[e];
    }
}

// ---------------- MFMA row GEMM: Y[r,0..64) = (A_f32[r,K] @ W[K,64]) * scale? ----
// 256 threads = 4 waves; wave = 32 rows x 64 cols via 16x16x32 bf16 MFMA.
// B-frags: one bf16x8 load each from pre-transposed Wt[col][k] in global (L2-hot).
// A-frags: f32 loads converted in-register via v_cvt_pk_bf16_f32.
// OUT_FP8: packs each output to fp8 e4m3 byte. No LDS, no barriers.
template <int K, bool SCALE, bool OUT_FP8, bool OUT_F32>
__global__ __launch_bounds__(256) void mfma_mm_kernel(const float* __restrict__ A,
                                                      const bf16_t* __restrict__ Wt,
                                                      const float* __restrict__ scale,
                                                      fp8_t* __restrict__ Y8,
                                                      float* __restrict__ Yf) {
    const int lane = threadIdx.x & 63;
    const int wid = threadIdx.x >> 6;
    const int g = lane >> 4;   // 0..3
    const int c = lane & 15;   // 0..15
    const int rbase = blockIdx.x * 128 + wid * 32;
    if (rbase >= N_NODES) return;

    constexpr int KS = K / 32;
    union frag_u { unsigned u[4]; bf16x8 v; };

    bf16x8 bfrag[4][KS];
#pragma unroll
    for (int ct = 0; ct < 4; ct++)
#pragma unroll
        for (int ks = 0; ks < KS; ks++)
            bfrag[ct][ks] = *reinterpret_cast<const bf16x8*>(
                Wt + (size_t)(ct * 16 + c) * K + ks * 32 + g * 8);

#pragma unroll
    for (int rt = 0; rt < 2; rt++) {
        const int r0 = rbase + rt * 16;

        bf16x8 afrag[KS];
#pragma unroll
        for (int ks = 0; ks < KS; ks++) {
            const float* ap = A + (size_t)(r0 + c) * K + ks * 32 + g * 8;
            float4 a0 = *reinterpret_cast<const float4*>(ap);
            float4 a1 = *reinterpret_cast<const float4*>(ap + 4);
            frag_u f;
            f.u[0] = cvt_pk_bf16(a0.x, a0.y);
            f.u[1] = cvt_pk_bf16(a0.z, a0.w);
            f.u[2] = cvt_pk_bf16(a1.x, a1.y);
            f.u[3] = cvt_pk_bf16(a1.z, a1.w);
            afrag[ks] = f.v;
        }

        float sc[4];
        if (SCALE) {
#pragma unroll
            for (int i = 0; i < 4; i++) sc[i] = scale[r0 + g * 4 + i];
        }

#pragma unroll
        for (int ct = 0; ct < 4; ct++) {
            f32x4 acc = {0.f, 0.f, 0.f, 0.f};
#pragma unroll
            for (int ks = 0; ks < KS; ks++)
                acc = __builtin_amdgcn_mfma_f32_16x16x32_bf16(afrag[ks], bfrag[ct][ks], acc, 0, 0, 0);
#pragma unroll
            for (int i = 0; i < 4; i++) {
                int row = r0 + g * 4 + i;
                float v = SCALE ? acc[i] * sc[i] : acc[i];
                size_t o = (size_t)row * HID_F + ct * 16 + c;
                if (OUT_FP8) Y8[o] = f32_to_fp8(v);
                if (OUT_F32) Yf[o] = v;
            }
        }
    }
}

// ---------------- fused gather + Euler-Maruyama update (fp8 m) ----------------
// One wave per dst node. 8 edges in flight: 8-lane group g takes edge jj+g,
// each lane loads uint2 (8B = 8 fp8 features at p=lane&7) — one 64B line per
// edge row. HW fp8->f32 unpack. 3-step shfl_xor reduce, 8-lane epilogue.
__global__ __launch_bounds__(256) void gather_update_kernel(const fp8_t* __restrict__ m,
                                                            const int* __restrict__ row_ptr,
                                                            const int* __restrict__ src_sorted,
                                                            const float* __restrict__ b,
                                                            float* __restrict__ x,
                                                            const float* __restrict__ dw) {
    int d = blockIdx.x * 4 + (threadIdx.x >> 6);
    int lane = threadIdx.x & 63;
    int g = lane >> 3;   // edge slot 0..7
    int p = lane & 7;    // feature octet: features [p*8, p*8+8)

    int beg = row_ptr[d];
    int end = row_ptr[d + 1];

    float acc[8];
#pragma unroll
    for (int i = 0; i < 8; i++) acc[i] = 0.f;

    for (int j = beg; j < end; j += 64) {
        int cnt = min(end - j, 64);
        int idx = (lane < cnt) ? src_sorted[j + lane] : 0;
#pragma unroll 4
        for (int jj = 0; jj < cnt; jj += 8) {
            int e = jj + g;
            int s = __shfl(idx, min(e, cnt - 1));
            if (e < cnt) {
                uint2 mv = *reinterpret_cast<const uint2*>(m + (size_t)s * HID_F + p * 8);
                f32x2 p0 = fp8x2_to_f32<false>(mv.x);
                f32x2 p1 = fp8x2_to_f32<true>(mv.x);
                f32x2 p2 = fp8x2_to_f32<false>(mv.y);
                f32x2 p3 = fp8x2_to_f32<true>(mv.y);
                acc[0] += p0.x; acc[1] += p0.y;
                acc[2] += p1.x; acc[3] += p1.y;
                acc[4] += p2.x; acc[5] += p2.y;
                acc[6] += p3.x; acc[7] += p3.y;
            }
        }
    }

#pragma unroll
    for (int i = 0; i < 8; i++) {
        acc[i] += __shfl_xor(acc[i], 8);
        acc[i] += __shfl_xor(acc[i], 16);
        acc[i] += __shfl_xor(acc[i], 32);
    }

    if (g == 0) {
        size_t o = (size_t)d * HID_F + p * 8;
        float4 x0 = *reinterpret_cast<const float4*>(x + o);
        float4 x1 = *reinterpret_cast<const float4*>(x + o + 4);
        float4 w0 = *reinterpret_cast<const float4*>(dw + o);
        float4 w1 = *reinterpret_cast<const float4*>(dw + o + 4);
        float s = DT * b[d];
        float4 r0, r1;
        r0.x = ONE_MINUS_DT * x0.x + s * acc[0] + C_NOISE * w0.x;
        r0.y = ONE_MINUS_DT * x0.y + s * acc[1] + C_NOISE * w0.y;
        r0.z = ONE_MINUS_DT * x0.z + s * acc[2] + C_NOISE * w0.z;
        r0.w = ONE_MINUS_DT * x0.w + s * acc[3] + C_NOISE * w0.w;
        r1.x = ONE_MINUS_DT * x1.x + s * acc[4] + C_NOISE * w1.x;
        r1.y = ONE_MINUS_DT * x1.y + s * acc[5] + C_NOISE * w1.y;
        r1.z = ONE_MINUS_DT * x1.z + s * acc[6] + C_NOISE * w1.z;
        r1.w = ONE_MINUS_DT * x1.w + s * acc[7] + C_NOISE * w1.w;
        *reinterpret_cast<float4*>(x + o) = r0;
        *reinterpret_cast<float4*>(x + o + 4) = r1;
    }
}

// ---------------- out projection (f32 regw): out[n,40] = x[n,64] @ W_out[64,40] ----
template <int K, int NCOL, int RPW>
__global__ __launch_bounds__(256) void regw_mm_kernel(const float* __restrict__ A,
                                                      const float* __restrict__ W,
                                                      float* __restrict__ Y,
                                                      int nwaves) {
    int lane = threadIdx.x & 63;
    int wid = __builtin_amdgcn_readfirstlane((blockIdx.x * 256 + threadIdx.x) >> 6);
    if (wid >= nwaves) return;

    float wreg[K];
#pragma unroll
    for (int k = 0; k < K; k++)
        wreg[k] = (lane < NCOL) ? W[k * NCOL + lane] : 0.0f;

    int r0 = wid * RPW;
#pragma unroll 1
    for (int rr = 0; rr < RPW; rr += 4) {
        int r = r0 + rr;
        const float* a0 = A + (size_t)(r + 0) * K;
        const float* a1 = A + (size_t)(r + 1) * K;
        const float* a2 = A + (size_t)(r + 2) * K;
        const float* a3 = A + (size_t)(r + 3) * K;
        float acc0 = 0.f, acc1 = 0.f, acc2 = 0.f, acc3 = 0.f;
#pragma unroll
        for (int k = 0; k < K; k++) {
            float w = wreg[k];
            acc0 = fmaf(a0[k], w, acc0);
            acc1 = fmaf(a1[k], w, acc1);
            acc2 = fmaf(a2[k], w, acc2);
            acc3 = fmaf(a3[k], w, acc3);
        }
        if (lane < NCOL) {
            Y[(size_t)(r + 0) * NCOL + lane] = acc0;
            Y[(size_t)(r + 1) * NCOL + lane] = acc1;
            Y[(size_t)(r + 2) * NCOL + lane] = acc2;
            Y[(size_t)(r + 3) * NCOL + lane] = acc3;
        }
    }
}

extern "C" void kernel_launch(void* const* d_in, const int* in_sizes, int n_in,
                              void* d_out, int out_size, void* d_ws, size_t ws_size,
                              hipStream_t stream) {
    const float* h     = (const float*)d_in[0];
    const float* W_in  = (const float*)d_in[1];
    const float* W_msg = (const float*)d_in[2];
    const float* W_out = (const float*)d_in[3];
    const float* dW    = (const float*)d_in[4];
    const int*   src   = (const int*)d_in[5];
    const int*   dst   = (const int*)d_in[6];
    float* out = (float*)d_out;

    const size_t NH = (size_t)N_NODES * HID_F;  // 6.4M
    const int NBLK = (N_NODES + 255) / 256;     // 391

    float*  x       = (float*)d_ws;                          // 6.4M f32 (25.6 MB)
    fp8_t*  m       = (fp8_t*)(x + NH);                      // 6.4M fp8 (6.4 MB)
    bf16_t* Win_t   = (bf16_t*)(m + NH);                     // 8192 bf16 (64 x 128)
    bf16_t* Wmsg_t  = Win_t + IN_F * HID_F;                  // 4096 bf16 (64 x 64)
    float*  a       = (float*)(Wmsg_t + HID_F * HID_F);      // 100K f
    float*  b       = a + N_NODES;                           // 100K f
    int* deg_out_i  = (int*)(b + N_NODES);                   // 100K i
    int* deg_in_i   = deg_out_i + N_NODES;                   // 100K i
    int* row_ptr    = deg_in_i + N_NODES;                    // 100K+1 i
    int* cursor     = row_ptr + N_NODES + 1;                 // 100K+1 i
    int* blocksum   = cursor + N_NODES + 1;                  // 391 i
    int* blockpfx   = blocksum + 512;                        // 391 i
    int* src_sorted = blockpfx + 512;                        // 1.6M i

    // ---- one-time: transposed bf16 weights ----
    transpose_w_kernel<<<dim3((IN_F * HID_F + 255) / 256), 256, 0, stream>>>(
        W_in, Win_t, IN_F, HID_F);
    transpose_w_kernel<<<dim3((HID_F * HID_F + 255) / 256), 256, 0, stream>>>(
        W_msg, Wmsg_t, HID_F, HID_F);

    // ---- one-time: degrees, scales, CSR ----
    (void)hipMemsetAsync(deg_out_i, 0, 2 * N_NODES * sizeof(int), stream);
    {
        dim3 ge((N_EDGES + 255) / 256);
        deg_kernel<<<ge, 256, 0, stream>>>(src, dst, deg_out_i, deg_in_i);
        scale_kernel<<<dim3(NBLK), 256, 0, stream>>>(deg_out_i, deg_in_i, a, b);
        scan_blocksum_kernel<<<dim3(NBLK), 256, 0, stream>>>(deg_in_i, blocksum);
        scan_top_kernel<<<1, 512, 0, stream>>>(blocksum, blockpfx, NBLK);
        scan_final_kernel<<<dim3(NBLK), 256, 0, stream>>>(deg_in_i, blockpfx, row_ptr, cursor);
        fill_kernel<<<ge, 256, 0, stream>>>(src, dst, cursor, src_sorted);
    }

    const dim3 g_mfma((N_NODES + 127) / 128);  // 782

    // ---- x = h @ W_in (f32 out) ----
    mfma_mm_kernel<IN_F, false, false, true><<<g_mfma, 256, 0, stream>>>(
        h, Win_t, nullptr, nullptr, x);

    // ---- 10 Euler-Maruyama steps ----
    const dim3 g_gather(N_NODES / 4);  // 25000
    for (int k = 0; k < N_STEPS; k++) {
        // m = fp8( a * (x @ W_msg) )   (A = f32 x, converted in-register)
        mfma_mm_kernel<HID_F, true, true, false><<<g_mfma, 256, 0, stream>>>(
            x, Wmsg_t, a, m, nullptr);
        // x = 0.9 x + 0.1 b * gather(m) + C_NOISE dW_k
        gather_update_kernel<<<g_gather, 256, 0, stream>>>(
            m, row_ptr, src_sorted, b, x, dW + (size_t)k * NH);
    }

    // ---- out = x @ W_out ----
    {
        const int nwaves = N_NODES / 8;  // 12500
        regw_mm_kernel<HID_F, OUT_F, 8><<<dim3((nwaves + 3) / 4), 256, 0, stream>>>(
            x, W_out, out, nwaves);
    }
}